// Round 1
// baseline (199.616 us; speedup 1.0000x reference)
//
#include <hip/hip_runtime.h>
#include <stdint.h>

#define NB 64
#define NN 1024
#define CDIM 512
#define KK 64

typedef __attribute__((ext_vector_type(4))) float f32x4;
typedef __attribute__((ext_vector_type(8))) short short8;

__device__ __forceinline__ unsigned short f2bf(float f) {
  unsigned int u = __float_as_uint(f);
  return (unsigned short)((u + 0x7fffu + ((u >> 16) & 1u)) >> 16);
}

// ---------------- K0: centers fp32 -> bf16 ----------------
__global__ __launch_bounds__(256) void k0_cvt(const float* __restrict__ cc,
                                              unsigned short* __restrict__ ccb) {
  int i = blockIdx.x * 256 + threadIdx.x;   // grid sized exactly KK*CDIM/256
  ccb[i] = f2bf(cc[i]);
}

// ---------------- K1: logits (MFMA) + softmax + a^T (bf16) + a_sum ----------------
// grid: (16 n-chunks, 64 b), 256 threads = 4 waves, wave owns 16 rows.
__global__ __launch_bounds__(256) void k1_assign(const float* __restrict__ x,
    const unsigned short* __restrict__ ccb, unsigned short* __restrict__ a_t,
    float* __restrict__ a_sum) {
  const int b = blockIdx.y;
  const int n0 = blockIdx.x << 6;
  const int tid = threadIdx.x;
  const int w = tid >> 6;
  const int l = tid & 63;
  const int lr = l & 15;
  const int lg = l >> 4;

  __shared__ unsigned short a_sm[KK * 64];  // [kc][r], byte-swizzled

  // A-frag source: lane -> row lr of this wave's 16-row stripe, c = cs + lg*8 + i
  const float* xr = x + ((size_t)b * NN + n0 + (w << 4) + lr) * CDIM + (lg << 3);
  // B-frag source: kc = t*16 + lr, c = cs + lg*8 + i
  const unsigned short* cb = ccb + lr * CDIM + (lg << 3);

  f32x4 acc0 = {0.f, 0.f, 0.f, 0.f}, acc1 = acc0, acc2 = acc0, acc3 = acc0;

  for (int cs = 0; cs < CDIM; cs += 32) {
    f32x4 xa = *(const f32x4*)(xr + cs);
    f32x4 xb = *(const f32x4*)(xr + cs + 4);
    short8 af;
    af[0] = (short)f2bf(xa[0]); af[1] = (short)f2bf(xa[1]);
    af[2] = (short)f2bf(xa[2]); af[3] = (short)f2bf(xa[3]);
    af[4] = (short)f2bf(xb[0]); af[5] = (short)f2bf(xb[1]);
    af[6] = (short)f2bf(xb[2]); af[7] = (short)f2bf(xb[3]);
    short8 b0 = *(const short8*)(cb + cs);
    short8 b1 = *(const short8*)(cb + 16 * CDIM + cs);
    short8 b2 = *(const short8*)(cb + 32 * CDIM + cs);
    short8 b3 = *(const short8*)(cb + 48 * CDIM + cs);
    acc0 = __builtin_amdgcn_mfma_f32_16x16x32_bf16(af, b0, acc0, 0, 0, 0);
    acc1 = __builtin_amdgcn_mfma_f32_16x16x32_bf16(af, b1, acc1, 0, 0, 0);
    acc2 = __builtin_amdgcn_mfma_f32_16x16x32_bf16(af, b2, acc2, 0, 0, 0);
    acc3 = __builtin_amdgcn_mfma_f32_16x16x32_bf16(af, b3, acc3, 0, 0, 0);
  }

  // D layout: lane holds logits[row=(l>>4)*4+j][kc=t*16+(l&15)] in acc_t[j]
  const int swzb = (lr & 7) << 3;   // (kc&7) identical for all 4 t at fixed lr
  float s0 = 0.f, s1 = 0.f, s2 = 0.f, s3 = 0.f;
  #pragma unroll
  for (int j = 0; j < 4; ++j) {
    float m = fmaxf(fmaxf(acc0[j], acc1[j]), fmaxf(acc2[j], acc3[j]));
    m = fmaxf(m, __shfl_xor(m, 1));
    m = fmaxf(m, __shfl_xor(m, 2));
    m = fmaxf(m, __shfl_xor(m, 4));
    m = fmaxf(m, __shfl_xor(m, 8));
    float e0 = __expf(acc0[j] - m);
    float e1 = __expf(acc1[j] - m);
    float e2 = __expf(acc2[j] - m);
    float e3 = __expf(acc3[j] - m);
    float s = e0 + e1 + e2 + e3;
    s += __shfl_xor(s, 1); s += __shfl_xor(s, 2);
    s += __shfl_xor(s, 4); s += __shfl_xor(s, 8);
    float inv = 1.0f / s;
    e0 *= inv; e1 *= inv; e2 *= inv; e3 *= inv;
    int r = (w << 4) + (lg << 2) + j;
    int rs = r ^ swzb;
    a_sm[( lr       << 6) + rs] = f2bf(e0);
    a_sm[((16 + lr) << 6) + rs] = f2bf(e1);
    a_sm[((32 + lr) << 6) + rs] = f2bf(e2);
    a_sm[((48 + lr) << 6) + rs] = f2bf(e3);
    s0 += e0; s1 += e1; s2 += e2; s3 += e3;
  }
  s0 += __shfl_xor(s0, 16); s0 += __shfl_xor(s0, 32);
  s1 += __shfl_xor(s1, 16); s1 += __shfl_xor(s1, 32);
  s2 += __shfl_xor(s2, 16); s2 += __shfl_xor(s2, 32);
  s3 += __shfl_xor(s3, 16); s3 += __shfl_xor(s3, 32);
  if (lg == 0) {
    atomicAdd(&a_sum[(b << 6) + lr],      s0);
    atomicAdd(&a_sum[(b << 6) + 16 + lr], s1);
    atomicAdd(&a_sum[(b << 6) + 32 + lr], s2);
    atomicAdd(&a_sum[(b << 6) + 48 + lr], s3);
  }
  __syncthreads();
  // coalesced write-out: a_t[b][kc][n0 + r], uint (2 bf16) granularity
  const unsigned int* au = (const unsigned int*)a_sm;
  for (int e = tid; e < 2048; e += 256) {
    int kc = e >> 5, n2 = e & 31;
    unsigned int v = au[(kc << 5) + (n2 ^ ((kc & 7) << 2))];
    *((unsigned int*)(a_t + (((size_t)((b << 6) + kc)) << 10) + n0) + n2) = v;
  }
}

// ---------------- K2: agg = a^T x, vlad = agg - a_sum*cc, sumsq ----------------
// grid: (8 c-slices, 64 b), 256 threads. thread: c = c0+(tid&63), kc-set = (tid>>6)*16.
__global__ __launch_bounds__(256) void k2_agg(const float* __restrict__ x,
    const unsigned short* __restrict__ a_t, const float* __restrict__ cc,
    const float* __restrict__ a_sum, float* __restrict__ out,
    float* __restrict__ sumsq) {
  const int b = blockIdx.y;
  const int c0 = blockIdx.x << 6;
  const int tid = threadIdx.x;
  const int cl = tid & 63;
  const int ks = (tid >> 6) << 4;

  __shared__ float a_sm[64 * 64];   // [n][kc] f32, quad-swizzled by (n>>1)&15
  __shared__ float x_sm[64 * 64];   // [n][c]
  __shared__ float red[4];

  float acc[16];
  #pragma unroll
  for (int i = 0; i < 16; ++i) acc[i] = 0.f;

  for (int nc = 0; nc < NN; nc += 64) {
    __syncthreads();
    // stage a chunk: global [kc][n] bf16 -> LDS [n][kc] f32 (swizzled banks)
    for (int e = tid; e < 2048; e += 256) {
      int kc = e >> 5, n2 = e & 31;
      unsigned int v = *(const unsigned int*)(a_t +
          (((size_t)((b << 6) + kc)) << 10) + nc + (n2 << 1));
      float lo = __uint_as_float(v << 16);
      float hi = __uint_as_float(v & 0xffff0000u);
      int kp = (kc & 3) | ((((kc >> 2) ^ (n2 & 15))) << 2);
      a_sm[((n2 << 1) << 6) + kp]       = lo;
      a_sm[(((n2 << 1) + 1) << 6) + kp] = hi;
    }
    // stage x chunk: [n][c] f32, linear (coalesced, conflict-free)
    for (int e = tid; e < 1024; e += 256) {
      int n = e >> 4, c4 = (e & 15) << 2;
      *(f32x4*)(x_sm + (n << 6) + c4) =
          *(const f32x4*)(x + ((size_t)b * NN + nc + n) * CDIM + c0 + c4);
    }
    __syncthreads();
    for (int n = 0; n < 64; ++n) {
      float xv = x_sm[(n << 6) + cl];
      int swz = ((n >> 1) & 15) << 2;
      #pragma unroll
      for (int u = 0; u < 4; ++u) {
        f32x4 av = *(const f32x4*)(a_sm + (n << 6) + ((ks + (u << 2)) ^ swz));
        acc[(u << 2) + 0] += av[0] * xv;
        acc[(u << 2) + 1] += av[1] * xv;
        acc[(u << 2) + 2] += av[2] * xv;
        acc[(u << 2) + 3] += av[3] * xv;
      }
    }
  }

  float lsum = 0.f;
  #pragma unroll
  for (int j = 0; j < 16; ++j) {
    int kc = ks + j;
    float v = acc[j] - a_sum[(b << 6) + kc] * cc[kc * CDIM + c0 + cl];
    out[((size_t)b << 15) + (kc << 9) + c0 + cl] = v;
    lsum += v * v;
  }
  lsum += __shfl_xor(lsum, 1);  lsum += __shfl_xor(lsum, 2);
  lsum += __shfl_xor(lsum, 4);  lsum += __shfl_xor(lsum, 8);
  lsum += __shfl_xor(lsum, 16); lsum += __shfl_xor(lsum, 32);
  if ((tid & 63) == 0) red[tid >> 6] = lsum;
  __syncthreads();
  if (tid == 0) atomicAdd(&sumsq[b], red[0] + red[1] + red[2] + red[3]);
}

// ---------------- K3: l2 normalize per batch ----------------
__global__ __launch_bounds__(256) void k3_norm(float* __restrict__ out,
                                               const float* __restrict__ sumsq) {
  int idx = blockIdx.x * 256 + threadIdx.x;   // grid exact: 2048*256 = 2M/4
  int b = idx >> 13;                          // 8192 float4 per batch
  float s = sumsq[b];
  float scale = 1.0f / sqrtf(fmaxf(s, 1e-12f));
  f32x4* io = (f32x4*)out;
  f32x4 v = io[idx];
  v[0] *= scale; v[1] *= scale; v[2] *= scale; v[3] *= scale;
  io[idx] = v;
}

extern "C" void kernel_launch(void* const* d_in, const int* in_sizes, int n_in,
                              void* d_out, int out_size, void* d_ws, size_t ws_size,
                              hipStream_t stream) {
  const float* x  = (const float*)d_in[0];
  const float* cc = (const float*)d_in[1];
  float* out = (float*)d_out;
  char* ws = (char*)d_ws;
  // ws layout: [a_t bf16 8MiB][ccb bf16 64KiB][a_sum 16KiB][sumsq 256B]
  unsigned short* a_t = (unsigned short*)ws;
  unsigned short* ccb = (unsigned short*)(ws + (8u << 20));
  float* a_sum = (float*)(ws + (8u << 20) + (64u << 10));
  float* sumsq = a_sum + NB * KK;

  hipMemsetAsync(a_sum, 0, NB * KK * 4 + NB * 4, stream);
  k0_cvt<<<dim3((KK * CDIM) / 256), 256, 0, stream>>>(cc, ccb);
  k1_assign<<<dim3(16, NB), 256, 0, stream>>>(x, ccb, a_t, a_sum);
  k2_agg<<<dim3(8, NB), 256, 0, stream>>>(x, a_t, cc, a_sum, out, sumsq);
  k3_norm<<<dim3(2048), 256, 0, stream>>>(out, sumsq);
}

// Round 3
// 95.297 us; speedup vs baseline: 2.0947x; 2.0947x over previous
//
#include <hip/hip_runtime.h>
#include <stdint.h>

#define NB 64
#define NN 1024
#define CDIM 512
#define KK 64

typedef __attribute__((ext_vector_type(4))) float f32x4;
typedef __attribute__((ext_vector_type(8))) short short8;
typedef __attribute__((ext_vector_type(4))) unsigned short u16x4;

__device__ __forceinline__ unsigned short f2bf(float f) {
  unsigned int u = __float_as_uint(f);
  return (unsigned short)((u + 0x7fffu + ((u >> 16) & 1u)) >> 16);
}

// ---------------- K0: centers fp32 -> bf16 ----------------
__global__ __launch_bounds__(256) void k0_cvt(const float* __restrict__ cc,
                                              unsigned short* __restrict__ ccb) {
  int i = blockIdx.x * 256 + threadIdx.x;   // grid sized exactly KK*CDIM/256
  ccb[i] = f2bf(cc[i]);
}

// ---------------- K1: logits (MFMA) + softmax + a^T (bf16) + a_sum ----------------
// grid: (16 n-chunks, 64 b), 256 threads = 4 waves, wave owns 16 rows.
__global__ __launch_bounds__(256) void k1_assign(const float* __restrict__ x,
    const unsigned short* __restrict__ ccb, unsigned short* __restrict__ a_t,
    float* __restrict__ a_sum) {
  const int b = blockIdx.y;
  const int n0 = blockIdx.x << 6;
  const int tid = threadIdx.x;
  const int w = tid >> 6;
  const int l = tid & 63;
  const int lr = l & 15;
  const int lg = l >> 4;

  __shared__ unsigned short a_sm[KK * 64];  // [kc][r], byte-swizzled

  // A-frag source: lane -> row lr of this wave's 16-row stripe, c = cs + lg*8 + i
  const float* xr = x + ((size_t)b * NN + n0 + (w << 4) + lr) * CDIM + (lg << 3);
  // B-frag source: kc = t*16 + lr, c = cs + lg*8 + i
  const unsigned short* cb = ccb + lr * CDIM + (lg << 3);

  f32x4 acc0 = {0.f, 0.f, 0.f, 0.f}, acc1 = acc0, acc2 = acc0, acc3 = acc0;

  for (int cs = 0; cs < CDIM; cs += 32) {
    f32x4 xa = *(const f32x4*)(xr + cs);
    f32x4 xb = *(const f32x4*)(xr + cs + 4);
    short8 af;
    af[0] = (short)f2bf(xa[0]); af[1] = (short)f2bf(xa[1]);
    af[2] = (short)f2bf(xa[2]); af[3] = (short)f2bf(xa[3]);
    af[4] = (short)f2bf(xb[0]); af[5] = (short)f2bf(xb[1]);
    af[6] = (short)f2bf(xb[2]); af[7] = (short)f2bf(xb[3]);
    short8 b0 = *(const short8*)(cb + cs);
    short8 b1 = *(const short8*)(cb + 16 * CDIM + cs);
    short8 b2 = *(const short8*)(cb + 32 * CDIM + cs);
    short8 b3 = *(const short8*)(cb + 48 * CDIM + cs);
    acc0 = __builtin_amdgcn_mfma_f32_16x16x32_bf16(af, b0, acc0, 0, 0, 0);
    acc1 = __builtin_amdgcn_mfma_f32_16x16x32_bf16(af, b1, acc1, 0, 0, 0);
    acc2 = __builtin_amdgcn_mfma_f32_16x16x32_bf16(af, b2, acc2, 0, 0, 0);
    acc3 = __builtin_amdgcn_mfma_f32_16x16x32_bf16(af, b3, acc3, 0, 0, 0);
  }

  // D layout: lane holds logits[row=(l>>4)*4+j][kc=t*16+(l&15)] in acc_t[j]
  const int swzb = (lr & 7) << 3;   // (kc&7) identical for all 4 t at fixed lr
  float s0 = 0.f, s1 = 0.f, s2 = 0.f, s3 = 0.f;
  #pragma unroll
  for (int j = 0; j < 4; ++j) {
    float m = fmaxf(fmaxf(acc0[j], acc1[j]), fmaxf(acc2[j], acc3[j]));
    m = fmaxf(m, __shfl_xor(m, 1));
    m = fmaxf(m, __shfl_xor(m, 2));
    m = fmaxf(m, __shfl_xor(m, 4));
    m = fmaxf(m, __shfl_xor(m, 8));
    float e0 = __expf(acc0[j] - m);
    float e1 = __expf(acc1[j] - m);
    float e2 = __expf(acc2[j] - m);
    float e3 = __expf(acc3[j] - m);
    float s = e0 + e1 + e2 + e3;
    s += __shfl_xor(s, 1); s += __shfl_xor(s, 2);
    s += __shfl_xor(s, 4); s += __shfl_xor(s, 8);
    float inv = 1.0f / s;
    e0 *= inv; e1 *= inv; e2 *= inv; e3 *= inv;
    int r = (w << 4) + (lg << 2) + j;
    int rs = r ^ swzb;
    a_sm[( lr       << 6) + rs] = f2bf(e0);
    a_sm[((16 + lr) << 6) + rs] = f2bf(e1);
    a_sm[((32 + lr) << 6) + rs] = f2bf(e2);
    a_sm[((48 + lr) << 6) + rs] = f2bf(e3);
    s0 += e0; s1 += e1; s2 += e2; s3 += e3;
  }
  s0 += __shfl_xor(s0, 16); s0 += __shfl_xor(s0, 32);
  s1 += __shfl_xor(s1, 16); s1 += __shfl_xor(s1, 32);
  s2 += __shfl_xor(s2, 16); s2 += __shfl_xor(s2, 32);
  s3 += __shfl_xor(s3, 16); s3 += __shfl_xor(s3, 32);
  if (lg == 0) {
    atomicAdd(&a_sum[(b << 6) + lr],      s0);
    atomicAdd(&a_sum[(b << 6) + 16 + lr], s1);
    atomicAdd(&a_sum[(b << 6) + 32 + lr], s2);
    atomicAdd(&a_sum[(b << 6) + 48 + lr], s3);
  }
  __syncthreads();
  // coalesced write-out: a_t[b][kc][n0 + r], uint (2 bf16) granularity
  const unsigned int* au = (const unsigned int*)a_sm;
  for (int e = tid; e < 2048; e += 256) {
    int kc = e >> 5, n2 = e & 31;
    unsigned int v = au[(kc << 5) + (n2 ^ ((kc & 7) << 2))];
    *((unsigned int*)(a_t + (((size_t)((b << 6) + kc)) << 10) + n0) + n2) = v;
  }
}

// ---------------- K2: agg = a^T x via MFMA, vlad = agg - a_sum*cc, sumsq ----------
// grid: (8 c-slices, 64 b), 256 threads = 4 waves.
// Wave w owns k-rows [16w,16w+16), all 64 c of the slice (4 c-tiles).
// A-frags (a_t, [k][n] bf16, contract-dim contiguous) load DIRECTLY from global.
// B-frags need x^T: stage transposed bf16 tile xT[64c][64n] in LDS per chunk,
// XOR-swizzled so b64 writes are ~2-way and b128 frag reads conflict-free.
__global__ __launch_bounds__(256) void k2_agg(const float* __restrict__ x,
    const unsigned short* __restrict__ a_t, const float* __restrict__ cc,
    const float* __restrict__ a_sum, float* __restrict__ out,
    float* __restrict__ sumsq) {
  const int b = blockIdx.y;
  const int c0 = blockIdx.x << 6;
  const int tid = threadIdx.x;
  const int w = tid >> 6;
  const int l = tid & 63;
  const int lr = l & 15;
  const int lg = l >> 4;

  __shared__ unsigned short xT[64 * 64];  // [c_loc][n_loc], swizzled
  __shared__ float red[4];

  f32x4 acc[4];
  #pragma unroll
  for (int i = 0; i < 4; ++i) acc[i] = (f32x4){0.f, 0.f, 0.f, 0.f};

  // staging thread mapping: c lane = tid&63 (coalesced), n-base = (tid>>6)*4
  const int cl = tid & 63;
  const int nb4 = (tid >> 6) << 2;
  const float* xb = x + (size_t)b * NN * CDIM + c0 + cl;
  const unsigned short* ar =
      a_t + (((size_t)(b << 6) + (w << 4) + lr) << 10) + (lg << 3);

  for (int nc = 0; nc < NN; nc += 64) {
    __syncthreads();
    // stage: x[nc..nc+64)[c0..c0+64) fp32 -> xT[c][n] bf16
    #pragma unroll
    for (int p = 0; p < 4; ++p) {
      int nl = nb4 + (p << 4);
      const float* xp = xb + (size_t)(nc + nl) * CDIM;
      float v0 = xp[0];
      float v1 = xp[CDIM];
      float v2 = xp[2 * CDIM];
      float v3 = xp[3 * CDIM];
      u16x4 pk;
      pk[0] = f2bf(v0); pk[1] = f2bf(v1); pk[2] = f2bf(v2); pk[3] = f2bf(v3);
      *(u16x4*)&xT[(cl << 6) + (nl ^ ((cl & 7) << 3))] = pk;
    }
    __syncthreads();
    // MFMA: 2 k-steps of 32, A from global (L2-hot), B from LDS
    #pragma unroll
    for (int ns = 0; ns < 64; ns += 32) {
      short8 af = *(const short8*)(ar + nc + ns);
      #pragma unroll
      for (int ct = 0; ct < 4; ++ct) {
        int crow = (ct << 4) + lr;
        short8 bf = *(const short8*)&xT[(crow << 6) +
                                        ((ns + (lg << 3)) ^ ((crow & 7) << 3))];
        acc[ct] = __builtin_amdgcn_mfma_f32_16x16x32_bf16(af, bf, acc[ct], 0, 0, 0);
      }
    }
  }

  // epilogue: D[row=k=16w+lg*4+j][col=c=c0+ct*16+lr]
  float lsum = 0.f;
  #pragma unroll
  for (int ct = 0; ct < 4; ++ct) {
    #pragma unroll
    for (int j = 0; j < 4; ++j) {
      int k = (w << 4) + (lg << 2) + j;
      int c = c0 + (ct << 4) + lr;
      float v = acc[ct][j] - a_sum[(b << 6) + k] * cc[k * CDIM + c];
      out[((size_t)b << 15) + (k << 9) + c] = v;
      lsum += v * v;
    }
  }
  lsum += __shfl_xor(lsum, 1);  lsum += __shfl_xor(lsum, 2);
  lsum += __shfl_xor(lsum, 4);  lsum += __shfl_xor(lsum, 8);
  lsum += __shfl_xor(lsum, 16); lsum += __shfl_xor(lsum, 32);
  if ((tid & 63) == 0) red[tid >> 6] = lsum;
  __syncthreads();
  if (tid == 0) atomicAdd(&sumsq[b], red[0] + red[1] + red[2] + red[3]);
}

// ---------------- K3: l2 normalize per batch ----------------
__global__ __launch_bounds__(256) void k3_norm(float* __restrict__ out,
                                               const float* __restrict__ sumsq) {
  int idx = blockIdx.x * 256 + threadIdx.x;   // grid exact: 2048*256 = 2M/4
  int b = idx >> 13;                          // 8192 float4 per batch
  float s = sumsq[b];
  float scale = 1.0f / sqrtf(fmaxf(s, 1e-12f));
  f32x4* io = (f32x4*)out;
  f32x4 v = io[idx];
  v[0] *= scale; v[1] *= scale; v[2] *= scale; v[3] *= scale;
  io[idx] = v;
}

extern "C" void kernel_launch(void* const* d_in, const int* in_sizes, int n_in,
                              void* d_out, int out_size, void* d_ws, size_t ws_size,
                              hipStream_t stream) {
  const float* x  = (const float*)d_in[0];
  const float* cc = (const float*)d_in[1];
  float* out = (float*)d_out;
  char* ws = (char*)d_ws;
  // ws layout: [a_t bf16 8MiB][ccb bf16 64KiB][a_sum 16KiB][sumsq 256B]
  unsigned short* a_t = (unsigned short*)ws;
  unsigned short* ccb = (unsigned short*)(ws + (8u << 20));
  float* a_sum = (float*)(ws + (8u << 20) + (64u << 10));
  float* sumsq = a_sum + NB * KK;

  (void)hipMemsetAsync(a_sum, 0, NB * KK * 4 + NB * 4, stream);
  k0_cvt<<<dim3((KK * CDIM) / 256), 256, 0, stream>>>(cc, ccb);
  k1_assign<<<dim3(16, NB), 256, 0, stream>>>(x, ccb, a_t, a_sum);
  k2_agg<<<dim3(8, NB), 256, 0, stream>>>(x, a_t, cc, a_sum, out, sumsq);
  k3_norm<<<dim3(2048), 256, 0, stream>>>(out, sumsq);
}